// Round 1
// baseline (538.519 us; speedup 1.0000x reference)
//
#include <hip/hip_runtime.h>

// VectorQuantizer: N=65536 rows (64*32*32), D=256, K=1024 codes, fp32.
// argmin_k ||x-e_k||^2 == argmax_k (x.e_k - 0.5*||e_k||^2).
// Plan: prep (zero per-row best + code half-norms) -> fused GEMM+argmax -> gather.

#define N_ROWS 65536
#define K_EMB  1024
#define D_DIM  256

#define BM 128
#define BN 128
#define BK 8

__device__ __forceinline__ unsigned int f32_sortable(float f) {
    unsigned int u = __float_as_uint(f);
    // monotone map: larger float -> larger uint (handles negatives)
    return (u & 0x80000000u) ? ~u : (u | 0x80000000u);
}

// 256 blocks x 256 threads = 65536 threads = 1024 waves.
// Each thread zeroes one packed-best slot; each wave computes 0.5*||e_row||^2.
__global__ void vq_prep_kernel(const float* __restrict__ emb,
                               unsigned long long* __restrict__ packed,
                               float* __restrict__ cnorm) {
    int gid  = blockIdx.x * blockDim.x + threadIdx.x;
    packed[gid] = 0ULL;                 // smaller than any sortable score
    int wave = gid >> 6;                // 0..1023 -> codebook row
    int lane = gid & 63;
    const float4* erow = (const float4*)(emb + wave * D_DIM);
    float4 v = erow[lane];              // 64 lanes x 4 floats = 256
    float s = v.x * v.x + v.y * v.y + v.z * v.z + v.w * v.w;
    #pragma unroll
    for (int off = 32; off > 0; off >>= 1)
        s += __shfl_down(s, off, 64);
    if (lane == 0) cnorm[wave] = 0.5f * s;
}

// 128x128 tile, BK=8, 256 threads, 8x8 micro-tile per thread.
__global__ __launch_bounds__(256, 2) void vq_gemm_argmax_kernel(
    const float* __restrict__ X, const float* __restrict__ E,
    const float* __restrict__ cnorm, unsigned long long* __restrict__ packed)
{
    __shared__ float As[BK][BM];                 // 4 KB, A^T tile
    __shared__ float Bs[BK][BN];                 // 4 KB, B^T tile
    __shared__ unsigned long long red[BM][16];   // 16 KB, argmax reduce

    const int bx = blockIdx.x;   // col block 0..7  (codes)
    const int by = blockIdx.y;   // row block 0..511 (x rows)
    const int t  = threadIdx.x;
    const int tx = t & 15;       // micro-tile col group
    const int ty = t >> 4;       // micro-tile row group

    const int row0 = by * BM;
    const int col0 = bx * BN;

    // staging loads: thread t loads one float4 of A and one of B per K-step
    const int lr = t >> 1;            // 0..127: tile row
    const int lc = (t & 1) * 4;       // 0 or 4: k offset within BK

    const float* Aptr = X + (size_t)(row0 + lr) * D_DIM + lc;
    const float* Bptr = E + (size_t)(col0 + lr) * D_DIM + lc;

    float acc[8][8];
    #pragma unroll
    for (int i = 0; i < 8; i++)
        #pragma unroll
        for (int j = 0; j < 8; j++) acc[i][j] = 0.0f;

    for (int kt = 0; kt < D_DIM; kt += BK) {
        float4 av = *(const float4*)(Aptr + kt);
        float4 bv = *(const float4*)(Bptr + kt);
        __syncthreads();
        As[lc + 0][lr] = av.x; As[lc + 1][lr] = av.y;
        As[lc + 2][lr] = av.z; As[lc + 3][lr] = av.w;
        Bs[lc + 0][lr] = bv.x; Bs[lc + 1][lr] = bv.y;
        Bs[lc + 2][lr] = bv.z; Bs[lc + 3][lr] = bv.w;
        __syncthreads();
        #pragma unroll
        for (int kk = 0; kk < BK; kk++) {
            float a[8], b[8];
            *(float4*)&a[0] = *(const float4*)&As[kk][ty * 8];
            *(float4*)&a[4] = *(const float4*)&As[kk][ty * 8 + 4];
            *(float4*)&b[0] = *(const float4*)&Bs[kk][tx * 8];
            *(float4*)&b[4] = *(const float4*)&Bs[kk][tx * 8 + 4];
            #pragma unroll
            for (int i = 0; i < 8; i++)
                #pragma unroll
                for (int j = 0; j < 8; j++)
                    acc[i][j] = fmaf(a[i], b[j], acc[i][j]);
        }
    }

    // epilogue: score = dot - 0.5*||e||^2 ; argmax packed as
    // (sortable(score) << 32) | (1023 - col)  -> max picks best score,
    // ties resolve to smallest col (matches jnp.argmin first-min).
    float cv[8];
    #pragma unroll
    for (int j = 0; j < 8; j++) cv[j] = cnorm[col0 + tx * 8 + j];

    #pragma unroll
    for (int i = 0; i < 8; i++) {
        unsigned long long best = 0ULL;
        #pragma unroll
        for (int j = 0; j < 8; j++) {
            float s = acc[i][j] - cv[j];
            unsigned long long p =
                ((unsigned long long)f32_sortable(s) << 32) |
                (unsigned long long)(K_EMB - 1 - (col0 + tx * 8 + j));
            best = (p > best) ? p : best;
        }
        red[ty * 8 + i][tx] = best;
    }
    __syncthreads();
    if (t < BM) {
        unsigned long long best = 0ULL;
        #pragma unroll
        for (int j = 0; j < 16; j++) {
            unsigned long long p = red[t][j];
            best = (p > best) ? p : best;
        }
        atomicMax(packed + row0 + t, best);
    }
}

// 4 rows per 256-thread block; 64 lanes x float4 = one 256-float row copy.
__global__ void vq_gather_kernel(const unsigned long long* __restrict__ packed,
                                 const float* __restrict__ emb,
                                 float* __restrict__ outq,
                                 float* __restrict__ outi)
{
    int t    = threadIdx.x;
    int row  = blockIdx.x * 4 + (t >> 6);
    int lane = t & 63;
    unsigned long long p = packed[row];
    int idx = (K_EMB - 1) - (int)(unsigned int)(p & 0xffffffffULL);
    const float4* src = (const float4*)(emb + (size_t)idx * D_DIM);
    float4* dst = (float4*)(outq + (size_t)row * D_DIM);
    dst[lane] = src[lane];
    if (lane == 0) outi[row] = (float)idx;
}

extern "C" void kernel_launch(void* const* d_in, const int* in_sizes, int n_in,
                              void* d_out, int out_size, void* d_ws, size_t ws_size,
                              hipStream_t stream) {
    const float* x   = (const float*)d_in[0];
    const float* emb = (const float*)d_in[1];
    float* outq = (float*)d_out;
    float* outi = outq + (size_t)N_ROWS * D_DIM;  // indices chunk, as floats

    unsigned long long* packed = (unsigned long long*)d_ws;  // 512 KB
    float* cnorm = (float*)((char*)d_ws + (size_t)N_ROWS * sizeof(unsigned long long));

    vq_prep_kernel<<<256, 256, 0, stream>>>(emb, packed, cnorm);

    dim3 grid(K_EMB / BN, N_ROWS / BM);  // (8, 512)
    vq_gemm_argmax_kernel<<<grid, 256, 0, stream>>>(x, emb, cnorm, packed);

    vq_gather_kernel<<<N_ROWS / 4, 256, 0, stream>>>(packed, emb, outq, outi);
}

// Round 2
// 302.215 us; speedup vs baseline: 1.7819x; 1.7819x over previous
//
#include <hip/hip_runtime.h>

// VectorQuantizer: N=65536 rows, D=256, K=1024 codes, fp32 in/out.
// argmin_k ||x-e_k||^2 == argmax_k (x.e_k - 0.5*||e_k||^2).
// bf16x3 split MFMA GEMM (hh+hl+lh) + per-(row,colblock) top-2 + exact fp32
// rescue for rows whose approx top-2 margin <= 0.01 (error bound ~25 sigma).

#define N_ROWS 65536
#define K_EMB  1024
#define D_DIM  256

typedef unsigned long long u64;
typedef __attribute__((ext_vector_type(8))) __bf16 bf16x8;
typedef __attribute__((ext_vector_type(16))) float f32x16;

__device__ __forceinline__ unsigned int f32_sortable(float f) {
    unsigned int u = __float_as_uint(f);
    return (u & 0x80000000u) ? ~u : (u | 0x80000000u);
}
__device__ __forceinline__ float f32_unsort(unsigned int u) {
    unsigned int v = (u & 0x80000000u) ? (u ^ 0x80000000u) : ~u;
    return __uint_as_float(v);
}
__device__ __forceinline__ unsigned int bf16_rne(float f) {
    unsigned int u = __float_as_uint(f);
    return (u + 0x7fffu + ((u >> 16) & 1u)) >> 16;
}

// ---- pass 0: split x into bf16 hi/lo (written into d_out as scratch) ----
__global__ void vq_split_x(const float* __restrict__ x,
                           unsigned short* __restrict__ xhi,
                           unsigned short* __restrict__ xlo) {
    int i = blockIdx.x * 256 + threadIdx.x;           // float4 index
    float4 v = ((const float4*)x)[i];
    unsigned int h0 = bf16_rne(v.x), h1 = bf16_rne(v.y);
    unsigned int h2 = bf16_rne(v.z), h3 = bf16_rne(v.w);
    float r0 = v.x - __uint_as_float(h0 << 16);
    float r1 = v.y - __uint_as_float(h1 << 16);
    float r2 = v.z - __uint_as_float(h2 << 16);
    float r3 = v.w - __uint_as_float(h3 << 16);
    ushort4 hv = make_ushort4((unsigned short)h0, (unsigned short)h1,
                              (unsigned short)h2, (unsigned short)h3);
    ushort4 lv = make_ushort4((unsigned short)bf16_rne(r0), (unsigned short)bf16_rne(r1),
                              (unsigned short)bf16_rne(r2), (unsigned short)bf16_rne(r3));
    ((ushort4*)xhi)[i] = hv;
    ((ushort4*)xlo)[i] = lv;
}

// ---- pass 0b: split codebook + exact fp32 half-norms ----
__global__ void vq_prep_e(const float* __restrict__ emb,
                          unsigned short* __restrict__ ehi,
                          unsigned short* __restrict__ elo,
                          float* __restrict__ cnorm) {
    int gid = blockIdx.x * 256 + threadIdx.x;
    int code = gid >> 6, lane = gid & 63;
    float4 v = ((const float4*)(emb + (size_t)code * D_DIM))[lane];
    unsigned int h0 = bf16_rne(v.x), h1 = bf16_rne(v.y);
    unsigned int h2 = bf16_rne(v.z), h3 = bf16_rne(v.w);
    float r0 = v.x - __uint_as_float(h0 << 16);
    float r1 = v.y - __uint_as_float(h1 << 16);
    float r2 = v.z - __uint_as_float(h2 << 16);
    float r3 = v.w - __uint_as_float(h3 << 16);
    ((ushort4*)(ehi + (size_t)code * D_DIM))[lane] =
        make_ushort4((unsigned short)h0, (unsigned short)h1,
                     (unsigned short)h2, (unsigned short)h3);
    ((ushort4*)(elo + (size_t)code * D_DIM))[lane] =
        make_ushort4((unsigned short)bf16_rne(r0), (unsigned short)bf16_rne(r1),
                     (unsigned short)bf16_rne(r2), (unsigned short)bf16_rne(r3));
    float s = v.x * v.x + v.y * v.y + v.z * v.z + v.w * v.w;
    #pragma unroll
    for (int off = 32; off > 0; off >>= 1) s += __shfl_down(s, off, 64);
    if (lane == 0) cnorm[code] = 0.5f * s;
}

// ---- pass 1: bf16x3 MFMA GEMM + fused per-block per-row top-2 ----
// Tile 128x128, 4 waves (2x2), each wave 2x2 of 32x32x16 MFMA, 3 terms.
// LDS chunk placement XOR-swizzled: data (row r, k-half h) lives at
// 16B-offset 2r + (h ^ (r&1))  -> conflict-free b128 fragment reads, and
// matches global_load_lds's wave-uniform-base + lane*16 contract.
union SMem {
    unsigned short stage[4][2048];   // Ah, Al, Bh, Bl: each 128x16 bf16 = 4KB
    float sc[64][129];               // epilogue score chunk (pad+1): 33KB
};

#define GLDS(gp, lp) __builtin_amdgcn_global_load_lds( \
    (const __attribute__((address_space(1))) void*)(gp), \
    (__attribute__((address_space(3))) void*)(lp), 16, 0, 0)

__global__ __launch_bounds__(256, 2) void vq_gemm(
    const unsigned short* __restrict__ xhi, const unsigned short* __restrict__ xlo,
    const unsigned short* __restrict__ ehi, const unsigned short* __restrict__ elo,
    const float* __restrict__ cnorm, u64* __restrict__ top2)
{
    __shared__ SMem sm;
    const int t = threadIdx.x;
    const int w = t >> 6, lane = t & 63;
    const int wrow = w >> 1, wcol = w & 1;
    const int row0 = blockIdx.y * 128, col0 = blockIdx.x * 128;

    // staging: thread t owns 16B chunk #t of each buffer
    const int sr  = t >> 1;
    const int skh = (t & 1) ^ (sr & 1);                 // inverse swizzle
    const size_t aoff = (size_t)(row0 + sr) * D_DIM + skh * 8;
    const size_t boff = (size_t)(col0 + sr) * D_DIM + skh * 8;
    const unsigned short* gAh = xhi + aoff;
    const unsigned short* gAl = xlo + aoff;
    const unsigned short* gBh = ehi + boff;
    const unsigned short* gBl = elo + boff;
    unsigned short* lAh = &sm.stage[0][0] + w * 512;    // wave-uniform bases
    unsigned short* lAl = &sm.stage[1][0] + w * 512;
    unsigned short* lBh = &sm.stage[2][0] + w * 512;
    unsigned short* lBl = &sm.stage[3][0] + w * 512;

    // fragment read offsets (16B units), swizzle-matched
    const int m = lane & 31, kh = lane >> 5;
    int offA[2], offB[2];
    #pragma unroll
    for (int rt = 0; rt < 2; rt++) {
        int rr = wrow * 64 + rt * 32 + m;
        offA[rt] = rr * 2 + (kh ^ (rr & 1));
    }
    #pragma unroll
    for (int ct = 0; ct < 2; ct++) {
        int cc = wcol * 64 + ct * 32 + m;
        offB[ct] = cc * 2 + (kh ^ (cc & 1));
    }
    const bf16x8* fAh = (const bf16x8*)&sm.stage[0][0];
    const bf16x8* fAl = (const bf16x8*)&sm.stage[1][0];
    const bf16x8* fBh = (const bf16x8*)&sm.stage[2][0];
    const bf16x8* fBl = (const bf16x8*)&sm.stage[3][0];

    f32x16 acc[2][2] = {};

    for (int kt = 0; kt < D_DIM; kt += 16) {
        GLDS(gAh, lAh); GLDS(gAl, lAl); GLDS(gBh, lBh); GLDS(gBl, lBl);
        gAh += 16; gAl += 16; gBh += 16; gBl += 16;
        __syncthreads();
        bf16x8 ah0 = fAh[offA[0]], ah1 = fAh[offA[1]];
        bf16x8 al0 = fAl[offA[0]], al1 = fAl[offA[1]];
        bf16x8 bh0 = fBh[offB[0]], bh1 = fBh[offB[1]];
        bf16x8 bl0 = fBl[offB[0]], bl1 = fBl[offB[1]];
        acc[0][0] = __builtin_amdgcn_mfma_f32_32x32x16_bf16(ah0, bh0, acc[0][0], 0, 0, 0);
        acc[0][1] = __builtin_amdgcn_mfma_f32_32x32x16_bf16(ah0, bh1, acc[0][1], 0, 0, 0);
        acc[1][0] = __builtin_amdgcn_mfma_f32_32x32x16_bf16(ah1, bh0, acc[1][0], 0, 0, 0);
        acc[1][1] = __builtin_amdgcn_mfma_f32_32x32x16_bf16(ah1, bh1, acc[1][1], 0, 0, 0);
        acc[0][0] = __builtin_amdgcn_mfma_f32_32x32x16_bf16(ah0, bl0, acc[0][0], 0, 0, 0);
        acc[0][1] = __builtin_amdgcn_mfma_f32_32x32x16_bf16(ah0, bl1, acc[0][1], 0, 0, 0);
        acc[1][0] = __builtin_amdgcn_mfma_f32_32x32x16_bf16(ah1, bl0, acc[1][0], 0, 0, 0);
        acc[1][1] = __builtin_amdgcn_mfma_f32_32x32x16_bf16(ah1, bl1, acc[1][1], 0, 0, 0);
        acc[0][0] = __builtin_amdgcn_mfma_f32_32x32x16_bf16(al0, bh0, acc[0][0], 0, 0, 0);
        acc[0][1] = __builtin_amdgcn_mfma_f32_32x32x16_bf16(al0, bh1, acc[0][1], 0, 0, 0);
        acc[1][0] = __builtin_amdgcn_mfma_f32_32x32x16_bf16(al1, bh0, acc[1][0], 0, 0, 0);
        acc[1][1] = __builtin_amdgcn_mfma_f32_32x32x16_bf16(al1, bh1, acc[1][1], 0, 0, 0);
        __syncthreads();
    }

    // epilogue: score = acc - 0.5||e||^2; per-row top2 over this block's 128
    // cols, processed in 2 chunks of 64 rows through LDS.
    float cn[2];
    cn[0] = cnorm[col0 + wcol * 64 + m];
    cn[1] = cnorm[col0 + wcol * 64 + 32 + m];

    const int s = t >> 2, q = t & 3;
    for (int c = 0; c < 2; c++) {   // c = rt (row-tile) chunk
        #pragma unroll
        for (int ct = 0; ct < 2; ct++) {
            #pragma unroll
            for (int reg = 0; reg < 16; reg++) {
                int rl = (reg & 3) + 8 * (reg >> 2) + 4 * kh;   // C/D row map
                sm.sc[wrow * 32 + rl][wcol * 64 + ct * 32 + m] = acc[c][ct][reg] - cn[ct];
            }
        }
        __syncthreads();
        u64 b = 0, b2 = 0;
        #pragma unroll 8
        for (int i = 0; i < 32; i++) {
            float f = sm.sc[s][q * 32 + i];
            u64 p = ((u64)f32_sortable(f) << 32) |
                    (u64)(unsigned int)(K_EMB - 1 - (col0 + q * 32 + i));
            if (p > b) { b2 = b; b = p; } else if (p > b2) { b2 = p; }
        }
        #pragma unroll
        for (int d = 1; d <= 2; d <<= 1) {
            u64 ob = (u64)__shfl_xor((long long)b, d, 64);
            u64 os = (u64)__shfl_xor((long long)b2, d, 64);
            u64 hb = b > ob ? b : ob;
            u64 hs = b > ob ? b2 : os;
            u64 lb = b > ob ? ob : b;
            b = hb; b2 = lb > hs ? lb : hs;
        }
        if (q == 0) {
            int grow = row0 + (s >> 5) * 64 + c * 32 + (s & 31);
            u64* dst = top2 + (size_t)grow * 16 + blockIdx.x * 2;
            dst[0] = b; dst[1] = b2;
        }
        __syncthreads();
    }
}

// ---- pass 2: global top-2 of 16 candidates, exact-fp32 rescue, gather ----
__global__ void vq_finish(const u64* __restrict__ top2, const float* __restrict__ x,
                          const float* __restrict__ emb, const float* __restrict__ cnorm,
                          float* __restrict__ outq, float* __restrict__ outi)
{
    const int t = threadIdx.x, w = t >> 6, lane = t & 63;
    const int row = blockIdx.x * 4 + w;
    u64 v = (lane < 16) ? top2[(size_t)row * 16 + lane] : 0ULL;
    u64 b = v;
    #pragma unroll
    for (int d = 1; d < 64; d <<= 1) {
        u64 o = (u64)__shfl_xor((long long)b, d, 64); b = o > b ? o : b;
    }
    u64 s = (v == b) ? 0ULL : v;
    #pragma unroll
    for (int d = 1; d < 64; d <<= 1) {
        u64 o = (u64)__shfl_xor((long long)s, d, 64); s = o > s ? o : s;
    }
    int winner = (K_EMB - 1) - (int)(unsigned int)(b & 0xffffffffULL);
    float fb = f32_unsort((unsigned int)(b >> 32));
    float fs = f32_unsort((unsigned int)(s >> 32));
    if (fb - fs <= 0.01f) {          // wave-uniform rescue (rare: ~0.1% rows)
        u64 mask = __ballot((lane < 16) &&
                            (f32_unsort((unsigned int)(v >> 32)) >= fb - 0.01f));
        float4 xv = ((const float4*)(x + (size_t)row * D_DIM))[lane];
        float bestS = -3.0e38f; int bestI = 0x7fffffff;
        while (mask) {
            int bl = __ffsll((unsigned long long)mask) - 1;
            mask &= mask - 1;
            u64 cv = (u64)__shfl((long long)v, bl, 64);
            int ci = (K_EMB - 1) - (int)(unsigned int)(cv & 0xffffffffULL);
            float4 ev = ((const float4*)(emb + (size_t)ci * D_DIM))[lane];
            float d = xv.x * ev.x + xv.y * ev.y + xv.z * ev.z + xv.w * ev.w;
            #pragma unroll
            for (int dd = 1; dd < 64; dd <<= 1) d += __shfl_xor(d, dd, 64);
            float sc = d - cnorm[ci];
            if (sc > bestS || (sc == bestS && ci < bestI)) { bestS = sc; bestI = ci; }
        }
        winner = bestI;
    }
    float4 qv = ((const float4*)(emb + (size_t)winner * D_DIM))[lane];
    ((float4*)(outq + (size_t)row * D_DIM))[lane] = qv;
    if (lane == 0) outi[row] = (float)winner;
}

extern "C" void kernel_launch(void* const* d_in, const int* in_sizes, int n_in,
                              void* d_out, int out_size, void* d_ws, size_t ws_size,
                              hipStream_t stream) {
    const float* x   = (const float*)d_in[0];
    const float* emb = (const float*)d_in[1];
    float* outq = (float*)d_out;
    float* outi = outq + (size_t)N_ROWS * D_DIM;

    // x_hi/x_lo staged inside d_out (67.1MB used of 67.37MB); overwritten by
    // vq_finish only after vq_gemm has consumed them (stream-ordered).
    unsigned short* xhi = (unsigned short*)d_out;
    unsigned short* xlo = xhi + (size_t)N_ROWS * D_DIM;

    u64* top2 = (u64*)d_ws;                                        // 8.39 MB
    unsigned short* ehi = (unsigned short*)((char*)d_ws + (size_t)N_ROWS * 16 * 8);
    unsigned short* elo = ehi + (size_t)K_EMB * D_DIM;             // 512 KB each
    float* cnorm = (float*)(elo + (size_t)K_EMB * D_DIM);          // 4 KB

    vq_split_x<<<N_ROWS * D_DIM / 4 / 256, 256, 0, stream>>>(x, xhi, xlo);
    vq_prep_e<<<K_EMB / 4, 256, 0, stream>>>(emb, ehi, elo, cnorm);
    vq_gemm<<<dim3(K_EMB / 128, N_ROWS / 128), 256, 0, stream>>>(xhi, xlo, ehi, elo, cnorm, top2);
    vq_finish<<<N_ROWS / 4, 256, 0, stream>>>(top2, x, emb, cnorm, outq, outi);
}